// Round 2
// baseline (3586.313 us; speedup 1.0000x reference)
//
#include <hip/hip_runtime.h>
#include <math.h>

#define B_ 4
#define NQ_ 19320
#define NV_ 19320
#define C_ 256
#define H_ 8
#define L_ 3
#define P_ 4
#define D_ 32
#define MTOT (B_*NQ_)   // 77280

// ---------------------------------------------------------------- reductions
__device__ __forceinline__ void block_reduce2(float& a, float& b, float* sm) {
    #pragma unroll
    for (int o = 32; o > 0; o >>= 1) {
        a += __shfl_down(a, o, 64);
        b += __shfl_down(b, o, 64);
    }
    int wave = threadIdx.x >> 6, lane = threadIdx.x & 63;
    __syncthreads();
    if (lane == 0) { sm[wave] = a; sm[wave + 4] = b; }
    __syncthreads();
    a = sm[0] + sm[1] + sm[2] + sm[3];
    b = sm[4] + sm[5] + sm[6] + sm[7];
}

// ------------------------------------------------- kernel 1: q = LN1(query)+pos
__global__ __launch_bounds__(256) void ln1_pos_kernel(
    const float* __restrict__ query, const float* __restrict__ pos,
    const float* __restrict__ w, const float* __restrict__ b,
    float* __restrict__ out)
{
    __shared__ float sm[8];
    size_t row = blockIdx.x;
    int t = threadIdx.x;
    float x = query[row * C_ + t];
    float s = x, s2 = x * x;
    block_reduce2(s, s2, sm);
    float m = s * (1.0f / C_);
    float v = s2 * (1.0f / C_) - m * m;
    float rs = rsqrtf(v + 1e-5f);
    out[row * C_ + t] = (x - m) * rs * w[t] + b[t] + pos[row * C_ + t];
}

// ---- kernel 2 (fused): off/attn projections + softmax + MSDA gather, in-place
// q lives in `io` (row read before row written; block touches only its row)
__global__ __launch_bounds__(256) void offattn_msda_kernel(
    float* __restrict__ io,
    const float* __restrict__ Woff, const float* __restrict__ boff,
    const float* __restrict__ Wattn, const float* __restrict__ battn,
    const float* __restrict__ ref_pts,
    const float* __restrict__ val)
{
    __shared__ float qs[C_];
    __shared__ float lw[192];
    __shared__ float as_[96];
    const float NRMW[3] = {160.f, 80.f, 40.f};
    const float NRMH[3] = {92.f, 46.f, 23.f};
    const int LW[3] = {160, 80, 40};
    const int LH[3] = {92, 46, 23};
    const int LS[3] = {0, 14720, 18400};
    size_t row = blockIdx.x;
    int t = threadIdx.x;
    qs[t] = io[row * C_ + t];
    __syncthreads();
    for (int col = t; col < 288; col += 256) {
        if (col < 192) {
            float acc = boff[col];
            #pragma unroll 8
            for (int c = 0; c < C_; ++c) acc += qs[c] * Woff[c * 192 + col];
            int rem = col % 24;            // col = h*24 + l*8 + p*2 + cc
            int l = rem >> 3;
            int cc = col & 1;
            float nrm = (cc == 0) ? NRMW[l] : NRMH[l];
            float rp = ref_pts[(row * L_ + l) * 2 + cc];
            lw[col] = rp + acc / nrm;
        } else {
            int j = col - 192;
            float acc = battn[j];
            #pragma unroll 8
            for (int c = 0; c < C_; ++c) acc += qs[c] * Wattn[c * 96 + j];
            as_[j] = acc;
        }
    }
    __syncthreads();
    if (t < H_) {
        float mx = -1e30f;
        #pragma unroll
        for (int j = 0; j < 12; ++j) mx = fmaxf(mx, as_[t * 12 + j]);
        float e[12], s = 0.f;
        #pragma unroll
        for (int j = 0; j < 12; ++j) { e[j] = __expf(as_[t * 12 + j] - mx); s += e[j]; }
        float inv = 1.0f / s;
        #pragma unroll
        for (int j = 0; j < 12; ++j) as_[t * 12 + j] = e[j] * inv;
    }
    __syncthreads();
    // ---- MSDA gather: thread t -> (h = t>>5, d = t&31), out col = t
    int h = t >> 5, d = t & 31;
    int b = (int)(row / NQ_);
    const float* lrow = lw + h * 24;
    const float* arow = as_ + h * 12;
    float acc = 0.f;
    #pragma unroll
    for (int l = 0; l < L_; ++l) {
        int Wl = LW[l], Hl = LH[l];
        const float* vbase = val + (((size_t)b * H_ + h) * NV_ + LS[l]) * D_ + d;
        #pragma unroll
        for (int p = 0; p < P_; ++p) {
            float lx = lrow[l * 8 + p * 2 + 0];
            float ly = lrow[l * 8 + p * 2 + 1];
            float a = arow[l * 4 + p];
            float x = lx * Wl - 0.5f, y = ly * Hl - 0.5f;
            float x0f = floorf(x), y0f = floorf(y);
            float wx = x - x0f, wy = y - y0f;
            int x0 = (int)x0f, y0 = (int)y0f;
            float w00 = (1.f - wx) * (1.f - wy) * a;
            float w10 = wx * (1.f - wy) * a;
            float w01 = (1.f - wx) * wy * a;
            float w11 = wx * wy * a;
            bool xin0 = (x0 >= 0) & (x0 < Wl), xin1 = (x0 + 1 >= 0) & (x0 + 1 < Wl);
            bool yin0 = (y0 >= 0) & (y0 < Hl), yin1 = (y0 + 1 >= 0) & (y0 + 1 < Hl);
            if (xin0 & yin0) acc += w00 * vbase[((size_t)y0 * Wl + x0) * D_];
            if (xin1 & yin0) acc += w10 * vbase[((size_t)y0 * Wl + x0 + 1) * D_];
            if (xin0 & yin1) acc += w01 * vbase[((size_t)(y0 + 1) * Wl + x0) * D_];
            if (xin1 & yin1) acc += w11 * vbase[((size_t)(y0 + 1) * Wl + x0 + 1) * D_];
        }
    }
    io[row * C_ + t] = acc;
}

// ----------------------------------------------------- generic 64x64 fp32 GEMM
// out = A[M,K] @ W[K,N] + bias; modes:
//  0: plain   1: scatter to (B,H,NV,D)   2: exact GELU   3: + res (may alias out)
__global__ __launch_bounds__(256) void gemm64(
    const float* __restrict__ A, const float* __restrict__ W,
    const float* __restrict__ bias, const float* __restrict__ res,
    float* __restrict__ out, int M, int N, int K, int mode)
{
    __shared__ float As[16][64];
    __shared__ float Bs[16][64];
    const int tid = threadIdx.x;
    const int bm = blockIdx.y * 64;
    const int bn = blockIdx.x * 64;
    const int tx = tid & 15, ty = tid >> 4;
    const int ar = tid >> 2;
    const int ak = (tid & 3) * 4;
    const int br = tid >> 4;
    const int bc = (tid & 15) * 4;
    float acc[4][4] = {};
    for (int k0 = 0; k0 < K; k0 += 16) {
        float4 av = make_float4(0.f, 0.f, 0.f, 0.f);
        if (bm + ar < M) av = *(const float4*)(A + (size_t)(bm + ar) * K + k0 + ak);
        As[ak + 0][ar] = av.x; As[ak + 1][ar] = av.y;
        As[ak + 2][ar] = av.z; As[ak + 3][ar] = av.w;
        float4 bv = *(const float4*)(W + (size_t)(k0 + br) * N + bn + bc);
        *(float4*)&Bs[br][bc] = bv;
        __syncthreads();
        #pragma unroll
        for (int k = 0; k < 16; ++k) {
            float a0 = As[k][ty * 4 + 0], a1 = As[k][ty * 4 + 1];
            float a2 = As[k][ty * 4 + 2], a3 = As[k][ty * 4 + 3];
            float b0 = Bs[k][tx * 4 + 0], b1 = Bs[k][tx * 4 + 1];
            float b2 = Bs[k][tx * 4 + 2], b3 = Bs[k][tx * 4 + 3];
            acc[0][0] += a0 * b0; acc[0][1] += a0 * b1; acc[0][2] += a0 * b2; acc[0][3] += a0 * b3;
            acc[1][0] += a1 * b0; acc[1][1] += a1 * b1; acc[1][2] += a1 * b2; acc[1][3] += a1 * b3;
            acc[2][0] += a2 * b0; acc[2][1] += a2 * b1; acc[2][2] += a2 * b2; acc[2][3] += a2 * b3;
            acc[3][0] += a3 * b0; acc[3][1] += a3 * b1; acc[3][2] += a3 * b2; acc[3][3] += a3 * b3;
        }
        __syncthreads();
    }
    #pragma unroll
    for (int i = 0; i < 4; ++i) {
        int row = bm + ty * 4 + i;
        if (row >= M) continue;
        #pragma unroll
        for (int j = 0; j < 4; ++j) {
            int col = bn + tx * 4 + j;
            float v = acc[i][j] + bias[col];
            if (mode == 0) {
                out[(size_t)row * N + col] = v;
            } else if (mode == 1) {
                int bb = row / NV_, n = row % NV_;
                int h = col >> 5, d = col & 31;
                out[(((size_t)bb * H_ + h) * NV_ + n) * D_ + d] = v;
            } else if (mode == 2) {
                out[(size_t)row * N + col] = 0.5f * v * (1.0f + erff(v * 0.70710678118654752f));
            } else {
                out[(size_t)row * N + col] = v + res[(size_t)row * N + col];
            }
        }
    }
}

// ------------------------- kernel 4: x = query + LN1(query) + proj ; q2 = LN2(x)
__global__ __launch_bounds__(256) void x_q2_kernel(
    const float* __restrict__ query, const float* __restrict__ proj,
    const float* __restrict__ w1, const float* __restrict__ b1,
    const float* __restrict__ w2, const float* __restrict__ b2,
    float* __restrict__ x_out, float* __restrict__ q2_out /* aliases proj */)
{
    __shared__ float sm[8];
    size_t row = blockIdx.x;
    int t = threadIdx.x;
    float qv = query[row * C_ + t];
    float pv = proj[row * C_ + t];
    float s = qv, s2 = qv * qv;
    block_reduce2(s, s2, sm);
    float m = s * (1.0f / C_);
    float v = s2 * (1.0f / C_) - m * m;
    float rs = rsqrtf(v + 1e-5f);
    float q1 = (qv - m) * rs * w1[t] + b1[t];
    float xv = qv + pv + q1;
    x_out[row * C_ + t] = xv;
    float sx = xv, sx2 = xv * xv;
    block_reduce2(sx, sx2, sm);
    float m2 = sx * (1.0f / C_);
    float v2 = sx2 * (1.0f / C_) - m2 * m2;
    float rs2 = rsqrtf(v2 + 1e-5f);
    q2_out[row * C_ + t] = (xv - m2) * rs2 * w2[t] + b2[t];
}

// ---------------------------------------------------------------------- launch
extern "C" void kernel_launch(void* const* d_in, const int* in_sizes, int n_in,
                              void* d_out, int out_size, void* d_ws, size_t ws_size,
                              hipStream_t stream) {
    const float* query  = (const float*)d_in[0];
    const float* value  = (const float*)d_in[1];
    const float* qpos   = (const float*)d_in[2];
    const float* refpts = (const float*)d_in[3];
    const float* ln1w = (const float*)d_in[6];
    const float* ln1b = (const float*)d_in[7];
    const float* ln2w = (const float*)d_in[8];
    const float* ln2b = (const float*)d_in[9];
    const float* Woff  = (const float*)d_in[10];
    const float* boff  = (const float*)d_in[11];
    const float* Wattn = (const float*)d_in[12];
    const float* battn = (const float*)d_in[13];
    const float* Wval  = (const float*)d_in[14];
    const float* bval  = (const float*)d_in[15];
    const float* Wout  = (const float*)d_in[16];
    const float* bout  = (const float*)d_in[17];
    const float* Wff1  = (const float*)d_in[18];
    const float* bff1  = (const float*)d_in[19];
    const float* Wff2  = (const float*)d_in[20];
    const float* bff2  = (const float*)d_in[21];

    const size_t SZ_ROW = (size_t)MTOT * C_;      // 19,783,680 floats (79.1 MB)
    float* wsA = (float*)d_ws;                    // val -> proj -> q2
    float* wsH = wsA + SZ_ROW;                    // FFN hidden chunk
    float* out = (float*)d_out;                   // q -> msda -> x -> final

    // FFN hidden chunk rows, sized from remaining workspace (>= 64, <= MTOT)
    size_t avail_floats = (ws_size / 4 > SZ_ROW) ? (ws_size / 4 - SZ_ROW) : 0;
    int chunk = (int)(avail_floats / 1024);
    if (chunk > MTOT) chunk = MTOT;
    if (chunk > 9660) chunk = 9660;               // cap: 8 chunks, 39.6 MB
    if (chunk < 64) chunk = 64;                   // last-resort floor

    // 1: q = LN1(query) + pos -> d_out
    ln1_pos_kernel<<<MTOT, 256, 0, stream>>>(query, qpos, ln1w, ln1b, out);
    // 2: val = value @ W_val + b_val (scattered B,H,NV,D) -> wsA
    dim3 g256(256 / 64, (MTOT + 63) / 64);
    gemm64<<<g256, 256, 0, stream>>>(value, Wval, bval, nullptr, wsA,
                                     MTOT, 256, 256, 1);
    // 3: fused off/attn/softmax + MSDA, in-place on d_out
    offattn_msda_kernel<<<MTOT, 256, 0, stream>>>(out, Woff, boff, Wattn, battn,
                                                  refpts, wsA);
    // 4: proj = msda @ W_out + b_out -> wsA (val dead)
    gemm64<<<g256, 256, 0, stream>>>(out, Wout, bout, nullptr, wsA,
                                     MTOT, 256, 256, 0);
    // 5: x = query + proj + LN1(query) -> d_out ; q2 = LN2(x) -> wsA
    x_q2_kernel<<<MTOT, 256, 0, stream>>>(query, wsA, ln1w, ln1b, ln2w, ln2b,
                                          out, wsA);
    // 6/7: FFN in chunks; hidden lives in wsH; FFN2 adds residual in-place
    for (int r0 = 0; r0 < MTOT; r0 += chunk) {
        int rows = (MTOT - r0 < chunk) ? (MTOT - r0) : chunk;
        const float* q2c = wsA + (size_t)r0 * C_;
        float* xc        = out + (size_t)r0 * C_;
        dim3 gf1(1024 / 64, (rows + 63) / 64);
        gemm64<<<gf1, 256, 0, stream>>>(q2c, Wff1, bff1, nullptr, wsH,
                                        rows, 1024, 256, 2);
        dim3 gf2(256 / 64, (rows + 63) / 64);
        gemm64<<<gf2, 256, 0, stream>>>(wsH, Wff2, bff2, xc, xc,
                                        rows, 256, 1024, 3);
    }
}

// Round 3
// 1992.819 us; speedup vs baseline: 1.7996x; 1.7996x over previous
//
#include <hip/hip_runtime.h>
#include <math.h>

#define B_ 4
#define NQ_ 19320
#define NV_ 19320
#define C_ 256
#define H_ 8
#define L_ 3
#define P_ 4
#define D_ 32
#define MTOT (B_*NQ_)        // 77280
#define MPAD 77312           // 604*128
#define MPAD2 77440          // MPAD + 128 safety rows (zeroed) for chunked staging overrun

typedef unsigned short u16;
typedef __attribute__((ext_vector_type(8))) short s8v;    // 8 bf16 in 4 VGPRs
typedef __attribute__((ext_vector_type(4))) float f4v;

__device__ __forceinline__ u16 f2bf(float f) {
    unsigned u = __float_as_uint(f);
    u += 0x7fffu + ((u >> 16) & 1u);          // RNE
    return (u16)(u >> 16);
}
__device__ __forceinline__ float bf2f(u16 u) {
    return __uint_as_float(((unsigned)u) << 16);
}

#define GLOAD_LDS16(g, l) __builtin_amdgcn_global_load_lds( \
    (const __attribute__((address_space(1))) void*)(g),     \
    (__attribute__((address_space(3))) void*)(l), 16, 0, 0)

// ---------------------------------------------------------------- reductions
__device__ __forceinline__ void block_reduce2(float& a, float& b, float* sm) {
    #pragma unroll
    for (int o = 32; o > 0; o >>= 1) {
        a += __shfl_down(a, o, 64);
        b += __shfl_down(b, o, 64);
    }
    int wave = threadIdx.x >> 6, lane = threadIdx.x & 63;
    __syncthreads();
    if (lane == 0) { sm[wave] = a; sm[wave + 4] = b; }
    __syncthreads();
    a = sm[0] + sm[1] + sm[2] + sm[3];
    b = sm[4] + sm[5] + sm[6] + sm[7];
}

// --------------------------------------------- value fp32 -> bf16 (padded rows 0)
__global__ __launch_bounds__(256) void cvtA_kernel(
    const float* __restrict__ src, u16* __restrict__ dst)
{
    size_t row = blockIdx.x;
    int t = threadIdx.x;
    float v = (row < MTOT) ? src[row * C_ + t] : 0.f;
    dst[row * C_ + t] = f2bf(v);
}

// ----------------------------- W[K,N] fp32 -> WT[N,K] bf16 (small, once per call)
__global__ __launch_bounds__(256) void cvtW_kernel(
    const float* __restrict__ W, u16* __restrict__ WT, int N, int K)
{
    int o = blockIdx.x * 256 + threadIdx.x;
    if (o >= N * K) return;
    int n = o / K, k = o % K;
    WT[o] = f2bf(W[(size_t)k * N + n]);
}

// ------------------------------------------------- kernel: q = LN1(query)+pos
__global__ __launch_bounds__(256) void ln1_pos_kernel(
    const float* __restrict__ query, const float* __restrict__ pos,
    const float* __restrict__ w, const float* __restrict__ b,
    float* __restrict__ out)
{
    __shared__ float sm[8];
    size_t row = blockIdx.x;
    int t = threadIdx.x;
    float x = query[row * C_ + t];
    float s = x, s2 = x * x;
    block_reduce2(s, s2, sm);
    float m = s * (1.0f / C_);
    float v = s2 * (1.0f / C_) - m * m;
    float rs = rsqrtf(v + 1e-5f);
    out[row * C_ + t] = (x - m) * rs * w[t] + b[t] + pos[row * C_ + t];
}

// ---- fused: off/attn projections + softmax + branchless MSDA gather
// reads q fp32 (qin), val bf16; writes msda result bf16 -> outA rows [0,MTOT)
__global__ __launch_bounds__(256) void offattn_msda_kernel(
    const float* __restrict__ qin,
    const float* __restrict__ Woff, const float* __restrict__ boff,
    const float* __restrict__ Wattn, const float* __restrict__ battn,
    const float* __restrict__ ref_pts,
    const u16* __restrict__ val, u16* __restrict__ outA)
{
    __shared__ float qs[C_];
    __shared__ float lw[192];
    __shared__ float as_[96];
    const float NRMW[3] = {160.f, 80.f, 40.f};
    const float NRMH[3] = {92.f, 46.f, 23.f};
    const int LW[3] = {160, 80, 40};
    const int LH[3] = {92, 46, 23};
    const int LS[3] = {0, 14720, 18400};
    size_t row = blockIdx.x;
    int t = threadIdx.x;
    qs[t] = qin[row * C_ + t];
    __syncthreads();
    for (int col = t; col < 288; col += 256) {
        if (col < 192) {
            float acc = boff[col];
            #pragma unroll 8
            for (int c = 0; c < C_; ++c) acc += qs[c] * Woff[c * 192 + col];
            int rem = col % 24;            // col = h*24 + l*8 + p*2 + cc
            int l = rem >> 3;
            int cc = col & 1;
            float nrm = (cc == 0) ? NRMW[l] : NRMH[l];
            float rp = ref_pts[(row * L_ + l) * 2 + cc];
            lw[col] = rp + acc / nrm;
        } else {
            int j = col - 192;
            float acc = battn[j];
            #pragma unroll 8
            for (int c = 0; c < C_; ++c) acc += qs[c] * Wattn[c * 96 + j];
            as_[j] = acc;
        }
    }
    __syncthreads();
    if (t < H_) {
        float mx = -1e30f;
        #pragma unroll
        for (int j = 0; j < 12; ++j) mx = fmaxf(mx, as_[t * 12 + j]);
        float e[12], s = 0.f;
        #pragma unroll
        for (int j = 0; j < 12; ++j) { e[j] = __expf(as_[t * 12 + j] - mx); s += e[j]; }
        float inv = 1.0f / s;
        #pragma unroll
        for (int j = 0; j < 12; ++j) as_[t * 12 + j] = e[j] * inv;
    }
    __syncthreads();
    // ---- branchless MSDA gather: thread t -> (h = t>>5, d = t&31)
    int h = t >> 5, d = t & 31;
    int b = (int)(row / NQ_);
    float acc = 0.f;
    #pragma unroll
    for (int l = 0; l < L_; ++l) {
        const int Wl = LW[l], Hl = LH[l];
        const u16* vbase = val + (((size_t)b * H_ + h) * NV_ + LS[l]) * D_ + d;
        #pragma unroll
        for (int p = 0; p < P_; ++p) {
            float lx = lw[h * 24 + l * 8 + p * 2 + 0];
            float ly = lw[h * 24 + l * 8 + p * 2 + 1];
            float a  = as_[h * 12 + l * 4 + p];
            float x = lx * Wl - 0.5f, y = ly * Hl - 0.5f;
            float x0f = floorf(x), y0f = floorf(y);
            float wx = x - x0f, wy = y - y0f;
            int x0 = (int)x0f, y0 = (int)y0f;
            int x1 = x0 + 1, y1 = y0 + 1;
            float vx0 = (x0 >= 0 && x0 < Wl) ? 1.f : 0.f;
            float vx1 = (x1 >= 0 && x1 < Wl) ? 1.f : 0.f;
            float vy0 = (y0 >= 0 && y0 < Hl) ? 1.f : 0.f;
            float vy1 = (y1 >= 0 && y1 < Hl) ? 1.f : 0.f;
            int cx0 = min(max(x0, 0), Wl - 1), cx1 = min(max(x1, 0), Wl - 1);
            int cy0 = min(max(y0, 0), Hl - 1), cy1 = min(max(y1, 0), Hl - 1);
            float f00 = bf2f(vbase[((size_t)cy0 * Wl + cx0) * D_]);
            float f10 = bf2f(vbase[((size_t)cy0 * Wl + cx1) * D_]);
            float f01 = bf2f(vbase[((size_t)cy1 * Wl + cx0) * D_]);
            float f11 = bf2f(vbase[((size_t)cy1 * Wl + cx1) * D_]);
            float w00 = (1.f - wx) * (1.f - wy) * vx0 * vy0;
            float w10 = wx * (1.f - wy) * vx1 * vy0;
            float w01 = (1.f - wx) * wy * vx0 * vy1;
            float w11 = wx * wy * vx1 * vy1;
            acc += a * (w00 * f00 + w10 * f10 + w01 * f01 + w11 * f11);
        }
    }
    outA[row * C_ + t] = f2bf(acc);
}

// --------------------------------------- bf16 MFMA GEMM, 128x128 tile, 4 waves
// out = A[M,K](bf16) @ BT[N,K]^T (bf16) + bias ; modes:
//  0: fp32 plain   1: bf16 scatter (B,H,NV,D)   2: GELU -> bf16   3: fp32 +res
__global__ __launch_bounds__(256) void gemm_mfma(
    const u16* __restrict__ A, const u16* __restrict__ BT,
    const float* __restrict__ bias, const float* __restrict__ res,
    void* __restrict__ outp, int M, int N, int K, int mode)
{
    __shared__ __align__(16) u16 As[128 * 32];
    __shared__ __align__(16) u16 Bs[128 * 32];
    const int tid = threadIdx.x;
    const int wave = tid >> 6, lane = tid & 63;
    const int bm = blockIdx.y * 128, bn = blockIdx.x * 128;
    const int wm = (wave >> 1) * 64, wn = (wave & 1) * 64;
    const int lr = lane & 15;     // row/col within 16-tile
    const int lq = lane >> 4;     // quad
    f4v acc[4][4] = {};

    for (int k0 = 0; k0 < K; k0 += 32) {
        #pragma unroll
        for (int s = 0; s < 2; ++s) {
            int r = wave * 2 + s;              // chunk: 1024 B of the 8 KB tile
            int e = r * 512 + lane * 8;        // bf16 element index
            int arow = e >> 5, acol = e & 31;
            GLOAD_LDS16(A  + (size_t)(bm + arow) * K + (k0 + acol), &As[r * 512]);
            GLOAD_LDS16(BT + (size_t)(bn + arow) * K + (k0 + acol), &Bs[r * 512]);
        }
        __syncthreads();
        s8v af[4], bfr[4];
        #pragma unroll
        for (int i = 0; i < 4; ++i)
            af[i] = *(const s8v*)&As[(wm + i * 16 + lr) * 32 + lq * 8];
        #pragma unroll
        for (int j = 0; j < 4; ++j)
            bfr[j] = *(const s8v*)&Bs[(wn + j * 16 + lr) * 32 + lq * 8];
        #pragma unroll
        for (int i = 0; i < 4; ++i)
            #pragma unroll
            for (int j = 0; j < 4; ++j)
                acc[i][j] = __builtin_amdgcn_mfma_f32_16x16x32_bf16(
                    af[i], bfr[j], acc[i][j], 0, 0, 0);
        __syncthreads();
    }
    // C/D: col = lane&15, row = quad*4 + reg (m89/m91-verified)
    #pragma unroll
    for (int i = 0; i < 4; ++i) {
        #pragma unroll
        for (int v = 0; v < 4; ++v) {
            int row = bm + wm + i * 16 + lq * 4 + v;
            if (row >= M) continue;
            #pragma unroll
            for (int j = 0; j < 4; ++j) {
                int col = bn + wn + j * 16 + lr;
                float x = acc[i][j][v] + bias[col];
                if (mode == 0) {
                    ((float*)outp)[(size_t)row * N + col] = x;
                } else if (mode == 1) {
                    int bb = row / NV_, n = row % NV_;
                    int h = col >> 5, d = col & 31;
                    ((u16*)outp)[(((size_t)bb * H_ + h) * NV_ + n) * D_ + d] = f2bf(x);
                } else if (mode == 2) {
                    float g = 0.5f * x * (1.0f + erff(x * 0.70710678118654752f));
                    ((u16*)outp)[(size_t)row * N + col] = f2bf(g);
                } else {
                    ((float*)outp)[(size_t)row * N + col] = x + res[(size_t)row * N + col];
                }
            }
        }
    }
}

// --------------- x = query + LN1(query) + proj ; x -> d_out, q2(bf16) -> Abuf
__global__ __launch_bounds__(256) void x_q2_kernel(
    const float* __restrict__ query, const float* __restrict__ proj,
    const float* __restrict__ w1, const float* __restrict__ b1,
    const float* __restrict__ w2, const float* __restrict__ b2,
    float* __restrict__ x_out /* aliases proj elementwise */,
    u16* __restrict__ q2_out)
{
    __shared__ float sm[8];
    size_t row = blockIdx.x;
    int t = threadIdx.x;
    float qv = query[row * C_ + t];
    float pv = proj[row * C_ + t];
    float s = qv, s2 = qv * qv;
    block_reduce2(s, s2, sm);
    float m = s * (1.0f / C_);
    float v = s2 * (1.0f / C_) - m * m;
    float rs = rsqrtf(v + 1e-5f);
    float q1 = (qv - m) * rs * w1[t] + b1[t];
    float xv = qv + pv + q1;
    x_out[row * C_ + t] = xv;
    float sx = xv, sx2 = xv * xv;
    block_reduce2(sx, sx2, sm);
    float m2 = sx * (1.0f / C_);
    float v2 = sx2 * (1.0f / C_) - m2 * m2;
    float rs2 = rsqrtf(v2 + 1e-5f);
    q2_out[row * C_ + t] = f2bf((xv - m2) * rs2 * w2[t] + b2[t]);
}

// ---------------------------------------------------------------------- launch
extern "C" void kernel_launch(void* const* d_in, const int* in_sizes, int n_in,
                              void* d_out, int out_size, void* d_ws, size_t ws_size,
                              hipStream_t stream) {
    const float* query  = (const float*)d_in[0];
    const float* value  = (const float*)d_in[1];
    const float* qpos   = (const float*)d_in[2];
    const float* refpts = (const float*)d_in[3];
    const float* ln1w = (const float*)d_in[6];
    const float* ln1b = (const float*)d_in[7];
    const float* ln2w = (const float*)d_in[8];
    const float* ln2b = (const float*)d_in[9];
    const float* Woff  = (const float*)d_in[10];
    const float* boff  = (const float*)d_in[11];
    const float* Wattn = (const float*)d_in[12];
    const float* battn = (const float*)d_in[13];
    const float* Wval  = (const float*)d_in[14];
    const float* bval  = (const float*)d_in[15];
    const float* Wout  = (const float*)d_in[16];
    const float* bout  = (const float*)d_in[17];
    const float* Wff1  = (const float*)d_in[18];
    const float* bff1  = (const float*)d_in[19];
    const float* Wff2  = (const float*)d_in[20];
    const float* bff2  = (const float*)d_in[21];

    // ---- workspace layout (bf16 units) ----
    u16* Abuf  = (u16*)d_ws;                          // [MPAD2,256]  39.65 MB
    u16* wsVal = Abuf  + (size_t)MPAD2 * C_;          // [B,H,NV,D]   39.57 MB
    u16* WvalT = wsVal + (size_t)B_ * H_ * NV_ * D_;  // [256,256]
    u16* WoutT = WvalT + 256 * 256;                   // [256,256]
    u16* Wff1T = WoutT + 256 * 256;                   // [1024,256]
    u16* Wff2T = Wff1T + 1024 * 256;                  // [256,1024]
    u16* wsH   = Wff2T + 1024 * 256;                  // FFN hidden chunk
    float* out = (float*)d_out;                       // q -> proj -> x -> final

    size_t used = (size_t)((char*)wsH - (char*)d_ws);
    size_t avail = (ws_size > used) ? ws_size - used : 0;
    int nc = 4;                                       // 19328*1024*2 = 39.6 MB
    if (avail < (size_t)19328 * 1024 * 2) nc = 8;     // 9728*1024*2  = 19.9 MB

    // weight conversions (tiny)
    cvtW_kernel<<<(256 * 256 + 255) / 256, 256, 0, stream>>>(Wval, WvalT, 256, 256);
    cvtW_kernel<<<(256 * 256 + 255) / 256, 256, 0, stream>>>(Wout, WoutT, 256, 256);
    cvtW_kernel<<<(1024 * 256 + 255) / 256, 256, 0, stream>>>(Wff1, Wff1T, 1024, 256);
    cvtW_kernel<<<(1024 * 256 + 255) / 256, 256, 0, stream>>>(Wff2, Wff2T, 256, 1024);
    // A = bf16(value), padded rows zero
    cvtA_kernel<<<MPAD2, 256, 0, stream>>>(value, Abuf);
    // q = LN1(query) + pos -> d_out
    ln1_pos_kernel<<<MTOT, 256, 0, stream>>>(query, qpos, ln1w, ln1b, out);
    // val = value @ W_val + b_val -> bf16 scattered (B,H,NV,D)
    {
        dim3 g(256 / 128, MPAD / 128);
        gemm_mfma<<<g, 256, 0, stream>>>(Abuf, WvalT, bval, nullptr, wsVal,
                                         MTOT, 256, 256, 1);
    }
    // fused off/attn/softmax + MSDA -> bf16 into Abuf
    offattn_msda_kernel<<<MTOT, 256, 0, stream>>>(out, Woff, boff, Wattn, battn,
                                                  refpts, wsVal, Abuf);
    // proj = msda @ W_out + b_out -> fp32 d_out
    {
        dim3 g(256 / 128, MPAD / 128);
        gemm_mfma<<<g, 256, 0, stream>>>(Abuf, WoutT, bout, nullptr, out,
                                         MTOT, 256, 256, 0);
    }
    // x = query + proj + LN1(query) -> d_out ; q2 = LN2(x) -> bf16 Abuf
    x_q2_kernel<<<MTOT, 256, 0, stream>>>(query, out, ln1w, ln1b, ln2w, ln2b,
                                          out, Abuf);
    // FFN chunks
    int chunk = MTOT / nc;
    for (int c = 0; c < nc; ++c) {
        int r0 = c * chunk;
        int gy = (chunk + 127) / 128;
        dim3 g1(1024 / 128, gy);
        gemm_mfma<<<g1, 256, 0, stream>>>(Abuf + (size_t)r0 * C_, Wff1T, bff1,
                                          nullptr, wsH, chunk, 1024, 256, 2);
        dim3 g2(256 / 128, gy);
        gemm_mfma<<<g2, 256, 0, stream>>>(wsH, Wff2T, bff2,
                                          out + (size_t)r0 * C_,
                                          out + (size_t)r0 * C_,
                                          chunk, 256, 1024, 3);
    }
}